// Round 7
// baseline (129.407 us; speedup 1.0000x reference)
//
#include <hip/hip_runtime.h>
#include <math.h>

// MultiWindowAttention B=4,L=2048,H=8,E=D=64 fp32; w = 32<<(h&3).
// Round 13: barrier-free, LDS-free main kernel (per-wave fragment streaming).
//   R8-R12 eliminated every other suspect: schedule (R8), staging amortization
//   (R9), prefetch depth (R10), barrier vmcnt-drain (R11), bytes/L2 (R12 main
//   didn't improve with half the bytes). The invariant across all of them is
//   the lockstep barrier-per-tile shared-LDS round structure -> per-round
//   bubbles paid by all waves, every round. This round removes the structure:
//   prep pass (unchanged, bit-identical) emits K as bf16 frag-linear images
//   and V^T as f16 [d][j] (ld=64) into ws; the main kernel then has each wave
//   independently process 16 q-rows, loading K fragments as coalesced 1KB
//   wave-loads and V^T fragments as 8B/lane loads STRAIGHT FROM ws INTO
//   REGISTERS. No __shared__, no __syncthreads, no double buffer. 1024
//   blocks x 4 waves = 4096 wave-tasks all resident (16 waves/CU): latency
//   hidden by TLP, balance by 4-classes-per-CU construction, L2 by pinning
//   one (b,hb) group (4 slices x 512KB = 2MB) per XCD via c&7.
//   Numerics: same ops, same order as R12 -> absmax unchanged.

#define LL 2048
#define HH 8
#define EE 64
#define DD 64
#define RS (HH * EE)   // 512 floats between consecutive seq positions

typedef __attribute__((ext_vector_type(8))) short short8;
typedef __attribute__((ext_vector_type(4))) float floatx4;
typedef __attribute__((ext_vector_type(4))) _Float16 half4;
typedef __attribute__((ext_vector_type(2))) __fp16 fp16x2;   // cvt_pkrtz return type

static __device__ __forceinline__ unsigned f2bf(float f) {
    union { float f; unsigned u; } v; v.f = f;
    return (v.u + 0x7fff + ((v.u >> 16) & 1)) >> 16;   // RNE
}
static __device__ __forceinline__ unsigned pack2(float a, float b) {
    return f2bf(a) | (f2bf(b) << 16);
}
static __device__ __forceinline__ unsigned packh2(float a, float b) {
    union { fp16x2 h; unsigned u; } v;
    v.h = __builtin_amdgcn_cvt_pkrtz(a, b);
    return v.u;
}

// ---- per-t4 fused compute: S^T += K.Q^T, mask, exp, P.V -> acc ----
// VLD = leading dim (shorts) of the V^T image; kbase/vbase may be LDS or global.
template<int VLD>
static __device__ __forceinline__ void compute_tile(
    int j0, const short* __restrict__ kbase, const short* __restrict__ vbase,
    int w, int qb, int iq, int quad, int l15,
    short8 qf0, short8 qf1, floatx4* __restrict__ acc, float& lsum)
{
#pragma unroll
    for (int t4 = 0; t4 < 4; ++t4) {
        const int jb = j0 + t4 * 16;
        if (jb > qb + 15 + w || jb + 15 < qb - w) continue;   // wave-uniform skip
        const bool needMask = ((jb + 15 - qb) > w) || ((qb + 15 - jb) > w);

        const short* kp = kbase + 1024 * t4 + 128 * quad + 8 * l15;
        short8 k0 = *(const short8*)kp;
        short8 k1 = *(const short8*)(kp + 512);
        floatx4 st = {};
        st = __builtin_amdgcn_mfma_f32_16x16x32_bf16(k0, qf0, st, 0, 0, 0);
        st = __builtin_amdgcn_mfma_f32_16x16x32_bf16(k1, qf1, st, 0, 0, 0);

        float pr[4];
        const int jq = jb + quad * 4;
#pragma unroll
        for (int r = 0; r < 4; ++r) {
            float x = st[r];
            if (needMask) {
                const int di = iq - (jq + r);
                x = (di <= w && di >= -w) ? x : -INFINITY;
            }
            pr[r] = __expf(x);
            lsum += pr[r];
        }
        half4 pf;
        {
            union { half4 v; unsigned u[2]; } pu;
            pu.u[0] = packh2(pr[0], pr[1]);
            pu.u[1] = packh2(pr[2], pr[3]);
            pf = pu.v;
        }
#pragma unroll
        for (int nt = 0; nt < 4; ++nt) {
            half4 vf = *(const half4*)(vbase + (nt * 16 + l15) * VLD + t4 * 16 + quad * 4);
            acc[nt] = __builtin_amdgcn_mfma_f32_16x16x16f16(pf, vf, acc[nt], 0, 0, 0);
        }
    }
}

// ============================ PREP KERNEL ============================
// One block per (b,h,jt) 64-row tile. Writes:
//   wsK[tile][4096 shorts] : K tile bf16, frag-linear (exact fragment image)
//   wsV[tile][4096 shorts] : V^T tile f16, [d][j] packed (ld=64)
__global__ __launch_bounds__(256, 8) void mwa_prep(
    const float* __restrict__ K, const float* __restrict__ V,
    short* __restrict__ wsK, short* __restrict__ wsV)
{
    const int t   = blockIdx.x;
    const int jt  = t & 31;
    const int h   = (t >> 5) & 7;
    const int b   = t >> 8;
    const int j0  = jt << 6;
    const int tid = threadIdx.x;

    const float* Kt = K + ((size_t)(b * LL + j0) * HH + h) * EE;
    const float* Vt = V + ((size_t)(b * LL + j0) * HH + h) * DD;
    short* wk = wsK + (size_t)((b * HH + h) * 32 + jt) * 4096;
    short* wv = wsV + (size_t)((b * HH + h) * 32 + jt) * 4096;

    __shared__ float sV[64 * 68];

    // K: frag-linear bf16 (2 units of 8 floats per thread)
#pragma unroll
    for (int uu = 0; uu < 2; ++uu) {
        const int u = tid + uu * 256;
        const int row = u >> 3, cg = u & 7;
        const float4* src = (const float4*)(Kt + (size_t)row * RS + cg * 8);
        float4 f0 = src[0], f1 = src[1];
        uint4 o = { pack2(f0.x,f0.y), pack2(f0.z,f0.w),
                    pack2(f1.x,f1.y), pack2(f1.z,f1.w) };
        *(uint4*)&wk[((((row >> 4) * 2 + (cg >> 2)) * 4 + (cg & 3)) * 16 + (row & 15)) * 8] = o;
    }

    // V: fp32 tile -> LDS (padded), then transposed f16 pairs -> ws
    {
        const int row = tid >> 2, dg = (tid & 3) << 4;
        const float4* src = (const float4*)(Vt + (size_t)row * RS + dg);
        float4 f0 = src[0], f1 = src[1], f2 = src[2], f3 = src[3];
        *(float4*)&sV[row * 68 + dg     ] = f0;
        *(float4*)&sV[row * 68 + dg + 4 ] = f1;
        *(float4*)&sV[row * 68 + dg + 8 ] = f2;
        *(float4*)&sV[row * 68 + dg + 12] = f3;
    }
    __syncthreads();
    {
        const int d = tid >> 2, jp = (tid & 3) << 4;
        unsigned o[8];
#pragma unroll
        for (int r = 0; r < 8; ++r)
            o[r] = packh2(sV[(jp + 2 * r) * 68 + d], sV[(jp + 2 * r + 1) * 68 + d]);
        *(uint4*)&wv[d * 64 + jp    ] = *(uint4*)&o[0];
        *(uint4*)&wv[d * 64 + jp + 8] = *(uint4*)&o[4];
    }
}

// ============================ MAIN KERNEL ============================
// Barrier-free, LDS-free: each wave owns 16 q-rows, streams K/V fragments
// from the prepped ws images directly into registers.
__global__ __launch_bounds__(256, 4) void mwa_r13(
    const float* __restrict__ Q,
    const short* __restrict__ wsK,
    const short* __restrict__ wsV,
    float* __restrict__ O)
{
    const int tid  = threadIdx.x;
    const int lane = tid & 63;
    const int wv   = tid >> 6;          // wave 0..3
    const int quad = lane >> 4;
    const int l15  = lane & 15;

    // ---- task decode: gid = k*256 + (blk5*8 + b*2 + hb) ----
    //   k = window class (h&3); same-CU blocks {c, c+256, c+512, c+768}
    //   span all 4 classes -> balanced. c&7 = b*2+hb -> one (b,hb) group
    //   (4 bf16 slices = 2MB) pinned per XCD -> L2-resident re-reads.
    const int gid  = blockIdx.x;
    const int k    = gid >> 8;
    const int c    = gid & 255;
    const int blk5 = c >> 3;            // 0..31: which 64-row band of the slice
    const int b    = (c >> 1) & 3;
    const int hb   = c & 1;
    const int h    = hb * 4 + k;
    const int w    = 32 << k;
    const int i0w  = blk5 * 64 + wv * 16;   // this wave's 16 q-rows

    const float* Qb  = Q + ((size_t)b * LL * HH + h) * EE;
    const short* wKt = wsK + (size_t)((b * HH + h) * 32) * 4096;
    const short* wVt = wsV + (size_t)((b * HH + h) * 32) * 4096;
    float*       Ob  = O + ((size_t)b * LL * HH + h) * DD;

    // ---- Q fragments: direct per-lane load + bf16 pack (pre-scaled 1/8) ----
    short8 qf0, qf1;
    {
        const float sc = 0.125f;    // 2^-3: exact in bf16, folds softmax scale
        const float* qrow = Qb + (size_t)(i0w + l15) * RS + quad * 8;
        float4 a0 = *(const float4*)(qrow);
        float4 a1 = *(const float4*)(qrow + 4);
        float4 b0 = *(const float4*)(qrow + 32);
        float4 b1 = *(const float4*)(qrow + 36);
        union { short8 s; unsigned u[4]; } q0u, q1u;
        q0u.u[0] = pack2(sc*a0.x, sc*a0.y); q0u.u[1] = pack2(sc*a0.z, sc*a0.w);
        q0u.u[2] = pack2(sc*a1.x, sc*a1.y); q0u.u[3] = pack2(sc*a1.z, sc*a1.w);
        q1u.u[0] = pack2(sc*b0.x, sc*b0.y); q1u.u[1] = pack2(sc*b0.z, sc*b0.w);
        q1u.u[2] = pack2(sc*b1.x, sc*b1.y); q1u.u[3] = pack2(sc*b1.z, sc*b1.w);
        qf0 = q0u.s; qf1 = q1u.s;
    }

    const int jt_lo = max(0, i0w - w) >> 6;
    const int jt_hi = min(LL - 1, i0w + 15 + w) >> 6;

    floatx4 acc[4] = {};
    float lsum = 0.f;
    const int iq = i0w + l15;    // this lane's query row (q = l15 in S^T)
    const int qb = i0w;          // wave's q-block base

    for (int jt = jt_lo; jt <= jt_hi; ++jt) {
        const short* kbase = wKt + (size_t)jt * 4096;
        const short* vbase = wVt + (size_t)jt * 4096;
        compute_tile<64>(jt << 6, kbase, vbase, w, qb, iq, quad, l15,
                         qf0, qf1, acc, lsum);
    }

    // ---- epilogue: finish l, normalize, store (per-wave) ----
    lsum += __shfl_xor(lsum, 16, 64);
    lsum += __shfl_xor(lsum, 32, 64);      // lane (q = l15): row-sum over all j
    float rinv[4];
#pragma unroll
    for (int r = 0; r < 4; ++r) {
        const float lr = __shfl(lsum, quad * 4 + r, 64);
        rinv[r] = 1.0f / lr;
    }
#pragma unroll
    for (int nt = 0; nt < 4; ++nt) {
#pragma unroll
        for (int r = 0; r < 4; ++r) {
            Ob[(size_t)(i0w + quad * 4 + r) * RS + nt * 16 + l15]
                = acc[nt][r] * rinv[r];
        }
    }
}

// ==================== FALLBACK (R11, fp32 staging, LDS path) ====================
#define K_BUF(cu)  (sAll + (cu) * 4096)
#define V_BUF(cu)  (sAll + 8192 + (cu) * 4608)

static __device__ __forceinline__ void barrier_nodrain() {
    asm volatile("s_waitcnt lgkmcnt(0)" ::: "memory");
    __builtin_amdgcn_s_barrier();
}

#define ISSUE_F(jn, kf0_, kf1_, vv_)                                            \
    {                                                                           \
        const float4* src_ = (const float4*)(Kb + (size_t)((jn) + rowp) * RS + cp); \
        kf0_ = src_[0]; kf1_ = src_[1];                                         \
        _Pragma("unroll")                                                       \
        for (int rr_ = 0; rr_ < 8; ++rr_)                                       \
            vv_[rr_] = Vb[(size_t)((jn) + wv * 8 + rr_) * RS + lane];           \
    }
#define STAGE_F(bufIdx, kf0_, kf1_, vv_)                                        \
    {                                                                           \
        uint4 u0_ = { pack2(kf0_.x,kf0_.y), pack2(kf0_.z,kf0_.w),               \
                      pack2(kf1_.x,kf1_.y), pack2(kf1_.z,kf1_.w) };             \
        *(uint4*)&K_BUF(bufIdx)[kWoff] = u0_;                                   \
        uint4 w0_ = { packh2(vv_[0],vv_[1]), packh2(vv_[2],vv_[3]),             \
                      packh2(vv_[4],vv_[5]), packh2(vv_[6],vv_[7]) };           \
        *(uint4*)&V_BUF(bufIdx)[vWoff] = w0_;                                   \
    }

__global__ __launch_bounds__(512, 4) void mwa_r11f(
    const float* __restrict__ Q,
    const float* __restrict__ K,
    const float* __restrict__ V,
    float* __restrict__ O)
{
    const int tid  = threadIdx.x;
    const int lane = tid & 63;
    const int wv   = tid >> 6;
    const int quad = lane >> 4;
    const int l15  = lane & 15;

    const int gid   = blockIdx.x;
    const int heavy = (gid >> 8) == 0;
    const int c     = gid & 255;
    const int it    = c >> 4;
    const int rem   = c & 15;
    const int b     = rem >> 2;
    const int z     = rem & 3;
    const int hb    = z >> 1;
    const int p     = z & 1;
    const int h     = hb * 4 + (heavy ? (3 - p) : p);
    const int i0    = it << 7;
    const int w     = 32 << (h & 3);

    alignas(16) __shared__ short sAll[17408];

    const float* Qb = Q + ((size_t)b * LL * HH + h) * EE;
    const float* Kb = K + ((size_t)b * LL * HH + h) * EE;
    const float* Vb = V + ((size_t)b * LL * HH + h) * DD;
    float*       Ob = O + ((size_t)b * LL * HH + h) * DD;

    {
        const float sc = 0.125f;
        const int row = tid >> 2, cc = (tid & 3) << 4;
        const float4* src = (const float4*)(Qb + (size_t)(i0 + row) * RS + cc);
        float4 f0 = src[0], f1 = src[1], f2 = src[2], f3 = src[3];
        uint4 u0 = { pack2(sc*f0.x,sc*f0.y), pack2(sc*f0.z,sc*f0.w),
                     pack2(sc*f1.x,sc*f1.y), pack2(sc*f1.z,sc*f1.w) };
        uint4 u1 = { pack2(sc*f2.x,sc*f2.y), pack2(sc*f2.z,sc*f2.w),
                     pack2(sc*f3.x,sc*f3.y), pack2(sc*f3.z,sc*f3.w) };
        uint4* dst = (uint4*)&sAll[row * 72 + cc];
        dst[0] = u0; dst[1] = u1;
    }
    __syncthreads();
    short8 qf0, qf1;
    {
        const short* qp = &sAll[(wv * 16 + l15) * 72 + quad * 8];
        qf0 = *(const short8*)qp;
        qf1 = *(const short8*)(qp + 32);
    }
    __syncthreads();

    const int jt_lo = max(0, i0 - w) >> 6;
    const int jt_hi = min(LL - 1, i0 + 127 + w) >> 6;
    const int n     = jt_hi - jt_lo + 1;

    const int rowp  = tid >> 3, cp = (tid & 7) << 3;
    const int jtw   = rowp >> 4, l15w = rowp & 15, ks = cp >> 5, q0w = (cp >> 3) & 3;
    const int kWoff = (((jtw * 2 + ks) * 4 + q0w) * 16 + l15w) * 8;
    const int vWoff = lane * 72 + wv * 8;

    float4 kA0, kA1; float vA[8];
    float4 kB0, kB1; float vB[8];
    ISSUE_F(jt_lo << 6, kA0, kA1, vA);
    STAGE_F(0, kA0, kA1, vA);
    if (n > 1) ISSUE_F((jt_lo + 1) << 6, kA0, kA1, vA);
    __syncthreads();

    floatx4 acc[4] = {};
    float lsum = 0.f;
    const int iq = i0 + wv * 16 + l15;
    const int qb = i0 + wv * 16;

    for (int s = 0; s < n; s += 2) {
        const int jt = jt_lo + s;
        if (s + 2 < n) ISSUE_F((jt + 2) << 6, kB0, kB1, vB);
        if (s + 1 < n) STAGE_F(1, kA0, kA1, vA);
        compute_tile<72>(jt << 6, K_BUF(0), V_BUF(0), w, qb, iq, quad, l15, qf0, qf1, acc, lsum);
        barrier_nodrain();

        if (s + 1 < n) {
            if (s + 3 < n) ISSUE_F((jt + 3) << 6, kA0, kA1, vA);
            if (s + 2 < n) STAGE_F(0, kB0, kB1, vB);
            compute_tile<72>((jt + 1) << 6, K_BUF(1), V_BUF(1), w, qb, iq, quad, l15, qf0, qf1, acc, lsum);
            barrier_nodrain();
        }
    }

    lsum += __shfl_xor(lsum, 16, 64);
    lsum += __shfl_xor(lsum, 32, 64);
    float rinv[4];
#pragma unroll
    for (int r = 0; r < 4; ++r) {
        const float lr = __shfl(lsum, quad * 4 + r, 64);
        rinv[r] = 1.0f / lr;
    }
#pragma unroll
    for (int nt = 0; nt < 4; ++nt) {
#pragma unroll
        for (int r = 0; r < 4; ++r) {
            Ob[(size_t)(i0 + wv * 16 + quad * 4 + r) * RS + nt * 16 + l15]
                = acc[nt][r] * rinv[r];
        }
    }
}

extern "C" void kernel_launch(void* const* d_in, const int* in_sizes, int n_in,
                              void* d_out, int out_size, void* d_ws, size_t ws_size,
                              hipStream_t stream)
{
    const float* Q = (const float*)d_in[0];
    const float* K = (const float*)d_in[1];
    const float* V = (const float*)d_in[2];
    float* O = (float*)d_out;

    const size_t wsNeed = (size_t)2 * 4 * 8 * 32 * 4096 * sizeof(short);  // 16 MiB
    if (ws_size >= wsNeed) {
        short* wsK = (short*)d_ws;
        short* wsV = wsK + (size_t)4 * 8 * 32 * 4096;
        hipLaunchKernelGGL(mwa_prep, dim3(1024), dim3(256), 0, stream, K, V, wsK, wsV);
        hipLaunchKernelGGL(mwa_r13, dim3(1024), dim3(256), 0, stream, Q, wsK, wsV, O);
    } else {
        hipLaunchKernelGGL(mwa_r11f, dim3(512), dim3(512), 0, stream, Q, K, V, O);
    }
}

// Round 8
// 110.178 us; speedup vs baseline: 1.1745x; 1.1745x over previous
//
#include <hip/hip_runtime.h>
#include <math.h>

// MultiWindowAttention B=4,L=2048,H=8,E=D=64 fp32; w = 32<<(h&3).
// Round 14: branchless flat-t inner loop + explicit 1-deep register prefetch.
//   R13 counters (first visible): FETCH 16.4MB (L2 pinning works, HBM is NOT
//   the limit), MfmaUtil 4.6 / VALUBusy 13.6 / Occ 24.6 -> latency-bound.
//   Cause: per-t4 `continue` band-skip branch boxes each iteration into a
//   serial {k-load -> MFMA -> exp -> v-load -> MFMA} chain (~500cy exposed),
//   and VGPR_Count=32 shows the compiler kept no loads in flight.
//   Fix: ws re-layout so each 16-col block t owns a contiguous 2KB region
//   (K frag at +0, V frag at +1024) -> inner loop indexes base+t*2048 with
//   NO branches (mask only at t==te_lo/te_hi, exact); explicit A/B register
//   sets with unroll-2 rotation issue block t+1's 6 loads before computing
//   block t. Output bit-identical to R13 (same ops, same order; the blocks
//   R14 skips were all-zero contributions in R13).
//   Everything else = R13: prep pass, barrier-free LDS-free main, task
//   decode with class balance + (b,hb)->XCD pinning.

#define LL 2048
#define HH 8
#define EE 64
#define DD 64
#define RS (HH * EE)   // 512 floats between consecutive seq positions

typedef __attribute__((ext_vector_type(8))) short short8;
typedef __attribute__((ext_vector_type(4))) float floatx4;
typedef __attribute__((ext_vector_type(4))) _Float16 half4;
typedef __attribute__((ext_vector_type(2))) __fp16 fp16x2;   // cvt_pkrtz return type

static __device__ __forceinline__ unsigned f2bf(float f) {
    union { float f; unsigned u; } v; v.f = f;
    return (v.u + 0x7fff + ((v.u >> 16) & 1)) >> 16;   // RNE
}
static __device__ __forceinline__ unsigned pack2(float a, float b) {
    return f2bf(a) | (f2bf(b) << 16);
}
static __device__ __forceinline__ unsigned packh2(float a, float b) {
    union { fp16x2 h; unsigned u; } v;
    v.h = __builtin_amdgcn_cvt_pkrtz(a, b);
    return v.u;
}

// ============================ PREP KERNEL ============================
// One block per (b,h,jt) 64-row tile. ws layout: per (b,h) slice,
// 128 t-units (16 j-cols each) x 2048 shorts:
//   [t*2048 + 0    .. +1024) : K fragment image (bf16, frag-linear)
//   [t*2048 + 1024 .. +2048) : V^T fragment image (f16, [d][j] ld=16)
__global__ __launch_bounds__(256, 8) void mwa_prep(
    const float* __restrict__ K, const float* __restrict__ V,
    short* __restrict__ ws)
{
    const int t   = blockIdx.x;
    const int jt  = t & 31;
    const int h   = (t >> 5) & 7;
    const int b   = t >> 8;
    const int j0  = jt << 6;
    const int tid = threadIdx.x;

    const float* Kt = K + ((size_t)(b * LL + j0) * HH + h) * EE;
    const float* Vt = V + ((size_t)(b * LL + j0) * HH + h) * DD;
    short* wsb = ws + (size_t)(b * HH + h) * 262144 + (size_t)jt * 4 * 2048;

    __shared__ float sV[64 * 68];

    // K: frag-linear bf16 (2 units of 8 floats per thread)
#pragma unroll
    for (int uu = 0; uu < 2; ++uu) {
        const int u = tid + uu * 256;
        const int row = u >> 3, cg = u & 7;
        const float4* src = (const float4*)(Kt + (size_t)row * RS + cg * 8);
        float4 f0 = src[0], f1 = src[1];
        uint4 o = { pack2(f0.x,f0.y), pack2(f0.z,f0.w),
                    pack2(f1.x,f1.y), pack2(f1.z,f1.w) };
        // t4 = row>>4, ks = cg>>2, q = cg&3, l15j = row&15
        *(uint4*)&wsb[(row >> 4) * 2048 + (cg >> 2) * 512 + (cg & 3) * 128 + (row & 15) * 8] = o;
    }

    // V: fp32 tile -> LDS (padded), then transposed f16 pairs -> ws
    {
        const int row = tid >> 2, dg = (tid & 3) << 4;
        const float4* src = (const float4*)(Vt + (size_t)row * RS + dg);
        float4 f0 = src[0], f1 = src[1], f2 = src[2], f3 = src[3];
        *(float4*)&sV[row * 68 + dg     ] = f0;
        *(float4*)&sV[row * 68 + dg + 4 ] = f1;
        *(float4*)&sV[row * 68 + dg + 8 ] = f2;
        *(float4*)&sV[row * 68 + dg + 12] = f3;
    }
    __syncthreads();
    {
        const int d = tid >> 2, t4 = tid & 3, jp = t4 << 4;
        unsigned o[8];
#pragma unroll
        for (int r = 0; r < 8; ++r)
            o[r] = packh2(sV[(jp + 2 * r) * 68 + d], sV[(jp + 2 * r + 1) * 68 + d]);
        short* dst = &wsb[t4 * 2048 + 1024 + d * 16];
        *(uint4*)(dst    ) = *(uint4*)&o[0];
        *(uint4*)(dst + 8) = *(uint4*)&o[4];
    }
}

// ============================ MAIN KERNEL ============================
// Barrier-free, LDS-free: each wave owns 16 q-rows; flat t-loop over 16-col
// blocks with explicit 1-deep A/B register prefetch from the ws images.
__global__ __launch_bounds__(256, 4) void mwa_r14(
    const float* __restrict__ Q,
    const short* __restrict__ ws,
    float* __restrict__ O)
{
    const int tid  = threadIdx.x;
    const int lane = tid & 63;
    const int wv   = tid >> 6;          // wave 0..3
    const int quad = lane >> 4;
    const int l15  = lane & 15;

    // ---- task decode (= R13): same-CU blocks span all 4 classes; c&7 pins
    //      one (b,hb) group (4 half-precision slices = 2MB) per XCD.
    const int gid  = blockIdx.x;
    const int k    = gid >> 8;
    const int c    = gid & 255;
    const int blk5 = c >> 3;            // 0..31: 64-row band
    const int b    = (c >> 1) & 3;
    const int hb   = c & 1;
    const int h    = hb * 4 + k;
    const int w    = 32 << k;
    const int i0w  = blk5 * 64 + wv * 16;   // this wave's 16 q-rows

    const float* Qb  = Q + ((size_t)b * LL * HH + h) * EE;
    const short* wsb = ws + (size_t)(b * HH + h) * 262144;
    float*       Ob  = O + ((size_t)b * LL * HH + h) * DD;

    // ---- Q fragments: direct per-lane load + bf16 pack (pre-scaled 1/8) ----
    short8 qf0, qf1;
    {
        const float sc = 0.125f;    // 2^-3: exact in bf16, folds softmax scale
        const float* qrow = Qb + (size_t)(i0w + l15) * RS + quad * 8;
        float4 a0 = *(const float4*)(qrow);
        float4 a1 = *(const float4*)(qrow + 4);
        float4 b0 = *(const float4*)(qrow + 32);
        float4 b1 = *(const float4*)(qrow + 36);
        union { short8 s; unsigned u[4]; } q0u, q1u;
        q0u.u[0] = pack2(sc*a0.x, sc*a0.y); q0u.u[1] = pack2(sc*a0.z, sc*a0.w);
        q0u.u[2] = pack2(sc*a1.x, sc*a1.y); q0u.u[3] = pack2(sc*a1.z, sc*a1.w);
        q1u.u[0] = pack2(sc*b0.x, sc*b0.y); q1u.u[1] = pack2(sc*b0.z, sc*b0.w);
        q1u.u[2] = pack2(sc*b1.x, sc*b1.y); q1u.u[3] = pack2(sc*b1.z, sc*b1.w);
        qf0 = q0u.s; qf1 = q1u.s;
    }

    const int qb    = i0w;
    const int iq    = i0w + l15;            // this lane's query row (q = l15 in S^T)
    const int te_lo = (qb - w) >> 4;        // masked edge blocks (exact)
    const int te_hi = (qb + 15 + w) >> 4;
    const int t_lo  = te_lo < 0 ? 0 : te_lo;
    const int t_hi  = te_hi > 127 ? 127 : te_hi;

    const int koff = quad * 128 + l15 * 8;          // K frag lane offset
    const int voff = 1024 + l15 * 16 + quad * 4;    // V frag lane offset

    floatx4 acc[4] = {};
    float lsum = 0.f;

    // named A/B prefetch sets (static names: no runtime-indexed reg arrays)
    short8 k0A, k1A, k0B, k1B;
    half4  v0A, v1A, v2A, v3A, v0B, v1B, v2B, v3B;

#define LOADT(S, tt)                                                          \
    {                                                                         \
        const short* base_ = wsb + (size_t)(tt) * 2048;                       \
        k0##S = *(const short8*)(base_ + koff);                               \
        k1##S = *(const short8*)(base_ + koff + 512);                         \
        v0##S = *(const half4*)(base_ + voff);                                \
        v1##S = *(const half4*)(base_ + voff + 256);                          \
        v2##S = *(const half4*)(base_ + voff + 512);                          \
        v3##S = *(const half4*)(base_ + voff + 768);                          \
    }

#define COMPUTET(S, tt)                                                       \
    {                                                                         \
        floatx4 st = {};                                                      \
        st = __builtin_amdgcn_mfma_f32_16x16x32_bf16(k0##S, qf0, st, 0, 0, 0);\
        st = __builtin_amdgcn_mfma_f32_16x16x32_bf16(k1##S, qf1, st, 0, 0, 0);\
        const bool needMask = ((tt) == te_lo) || ((tt) == te_hi);             \
        const int jq = (tt) * 16 + quad * 4;                                  \
        float pr[4];                                                          \
        _Pragma("unroll")                                                     \
        for (int r = 0; r < 4; ++r) {                                         \
            float x = st[r];                                                  \
            if (needMask) {                                                   \
                const int di = iq - (jq + r);                                 \
                x = (di <= w && di >= -w) ? x : -INFINITY;                    \
            }                                                                 \
            pr[r] = __expf(x);                                                \
            lsum += pr[r];                                                    \
        }                                                                     \
        half4 pf;                                                             \
        {                                                                     \
            union { half4 v; unsigned u[2]; } pu;                             \
            pu.u[0] = packh2(pr[0], pr[1]);                                   \
            pu.u[1] = packh2(pr[2], pr[3]);                                   \
            pf = pu.v;                                                        \
        }                                                                     \
        acc[0] = __builtin_amdgcn_mfma_f32_16x16x16f16(pf, v0##S, acc[0], 0, 0, 0); \
        acc[1] = __builtin_amdgcn_mfma_f32_16x16x16f16(pf, v1##S, acc[1], 0, 0, 0); \
        acc[2] = __builtin_amdgcn_mfma_f32_16x16x16f16(pf, v2##S, acc[2], 0, 0, 0); \
        acc[3] = __builtin_amdgcn_mfma_f32_16x16x16f16(pf, v3##S, acc[3], 0, 0, 0); \
    }

    int t = t_lo;
    LOADT(A, t);
    while (t + 1 <= t_hi) {
        LOADT(B, t + 1);
        COMPUTET(A, t);
        if (t + 2 <= t_hi) LOADT(A, t + 2);
        COMPUTET(B, t + 1);
        t += 2;
    }
    if (t <= t_hi) COMPUTET(A, t);

#undef LOADT
#undef COMPUTET

    // ---- epilogue: finish l, normalize, store (per-wave) ----
    lsum += __shfl_xor(lsum, 16, 64);
    lsum += __shfl_xor(lsum, 32, 64);      // lane (q = l15): row-sum over all j
    float rinv[4];
#pragma unroll
    for (int r = 0; r < 4; ++r) {
        const float lr = __shfl(lsum, quad * 4 + r, 64);
        rinv[r] = 1.0f / lr;
    }
#pragma unroll
    for (int nt = 0; nt < 4; ++nt) {
#pragma unroll
        for (int r = 0; r < 4; ++r) {
            Ob[(size_t)(i0w + quad * 4 + r) * RS + nt * 16 + l15]
                = acc[nt][r] * rinv[r];
        }
    }
}

// ==================== FALLBACK (R11, fp32 staging, LDS path) ====================
#define K_BUF(cu)  (sAll + (cu) * 4096)
#define V_BUF(cu)  (sAll + 8192 + (cu) * 4608)

static __device__ __forceinline__ void barrier_nodrain() {
    asm volatile("s_waitcnt lgkmcnt(0)" ::: "memory");
    __builtin_amdgcn_s_barrier();
}

static __device__ __forceinline__ void compute_tile72(
    int j0, const short* __restrict__ kbase, const short* __restrict__ vbase,
    int w, int qb, int iq, int quad, int l15,
    short8 qf0, short8 qf1, floatx4* __restrict__ acc, float& lsum)
{
#pragma unroll
    for (int t4 = 0; t4 < 4; ++t4) {
        const int jb = j0 + t4 * 16;
        if (jb > qb + 15 + w || jb + 15 < qb - w) continue;
        const bool needMask = ((jb + 15 - qb) > w) || ((qb + 15 - jb) > w);

        const short* kp = kbase + 1024 * t4 + 128 * quad + 8 * l15;
        short8 k0 = *(const short8*)kp;
        short8 k1 = *(const short8*)(kp + 512);
        floatx4 st = {};
        st = __builtin_amdgcn_mfma_f32_16x16x32_bf16(k0, qf0, st, 0, 0, 0);
        st = __builtin_amdgcn_mfma_f32_16x16x32_bf16(k1, qf1, st, 0, 0, 0);

        float pr[4];
        const int jq = jb + quad * 4;
#pragma unroll
        for (int r = 0; r < 4; ++r) {
            float x = st[r];
            if (needMask) {
                const int di = iq - (jq + r);
                x = (di <= w && di >= -w) ? x : -INFINITY;
            }
            pr[r] = __expf(x);
            lsum += pr[r];
        }
        half4 pf;
        {
            union { half4 v; unsigned u[2]; } pu;
            pu.u[0] = packh2(pr[0], pr[1]);
            pu.u[1] = packh2(pr[2], pr[3]);
            pf = pu.v;
        }
#pragma unroll
        for (int nt = 0; nt < 4; ++nt) {
            half4 vf = *(const half4*)(vbase + (nt * 16 + l15) * 72 + t4 * 16 + quad * 4);
            acc[nt] = __builtin_amdgcn_mfma_f32_16x16x16f16(pf, vf, acc[nt], 0, 0, 0);
        }
    }
}

#define ISSUE_F(jn, kf0_, kf1_, vv_)                                            \
    {                                                                           \
        const float4* src_ = (const float4*)(Kb + (size_t)((jn) + rowp) * RS + cp); \
        kf0_ = src_[0]; kf1_ = src_[1];                                         \
        _Pragma("unroll")                                                       \
        for (int rr_ = 0; rr_ < 8; ++rr_)                                       \
            vv_[rr_] = Vb[(size_t)((jn) + wv * 8 + rr_) * RS + lane];           \
    }
#define STAGE_F(bufIdx, kf0_, kf1_, vv_)                                        \
    {                                                                           \
        uint4 u0_ = { pack2(kf0_.x,kf0_.y), pack2(kf0_.z,kf0_.w),               \
                      pack2(kf1_.x,kf1_.y), pack2(kf1_.z,kf1_.w) };             \
        *(uint4*)&K_BUF(bufIdx)[kWoff] = u0_;                                   \
        uint4 w0_ = { packh2(vv_[0],vv_[1]), packh2(vv_[2],vv_[3]),             \
                      packh2(vv_[4],vv_[5]), packh2(vv_[6],vv_[7]) };           \
        *(uint4*)&V_BUF(bufIdx)[vWoff] = w0_;                                   \
    }

__global__ __launch_bounds__(512, 4) void mwa_r11f(
    const float* __restrict__ Q,
    const float* __restrict__ K,
    const float* __restrict__ V,
    float* __restrict__ O)
{
    const int tid  = threadIdx.x;
    const int lane = tid & 63;
    const int wv   = tid >> 6;
    const int quad = lane >> 4;
    const int l15  = lane & 15;

    const int gid   = blockIdx.x;
    const int heavy = (gid >> 8) == 0;
    const int c     = gid & 255;
    const int it    = c >> 4;
    const int rem   = c & 15;
    const int b     = rem >> 2;
    const int z     = rem & 3;
    const int hb    = z >> 1;
    const int p     = z & 1;
    const int h     = hb * 4 + (heavy ? (3 - p) : p);
    const int i0    = it << 7;
    const int w     = 32 << (h & 3);

    alignas(16) __shared__ short sAll[17408];

    const float* Qb = Q + ((size_t)b * LL * HH + h) * EE;
    const float* Kb = K + ((size_t)b * LL * HH + h) * EE;
    const float* Vb = V + ((size_t)b * LL * HH + h) * DD;
    float*       Ob = O + ((size_t)b * LL * HH + h) * DD;

    {
        const float sc = 0.125f;
        const int row = tid >> 2, cc = (tid & 3) << 4;
        const float4* src = (const float4*)(Qb + (size_t)(i0 + row) * RS + cc);
        float4 f0 = src[0], f1 = src[1], f2 = src[2], f3 = src[3];
        uint4 u0 = { pack2(sc*f0.x,sc*f0.y), pack2(sc*f0.z,sc*f0.w),
                     pack2(sc*f1.x,sc*f1.y), pack2(sc*f1.z,sc*f1.w) };
        uint4 u1 = { pack2(sc*f2.x,sc*f2.y), pack2(sc*f2.z,sc*f2.w),
                     pack2(sc*f3.x,sc*f3.y), pack2(sc*f3.z,sc*f3.w) };
        uint4* dst = (uint4*)&sAll[row * 72 + cc];
        dst[0] = u0; dst[1] = u1;
    }
    __syncthreads();
    short8 qf0, qf1;
    {
        const short* qp = &sAll[(wv * 16 + l15) * 72 + quad * 8];
        qf0 = *(const short8*)qp;
        qf1 = *(const short8*)(qp + 32);
    }
    __syncthreads();

    const int jt_lo = max(0, i0 - w) >> 6;
    const int jt_hi = min(LL - 1, i0 + 127 + w) >> 6;
    const int n     = jt_hi - jt_lo + 1;

    const int rowp  = tid >> 3, cp = (tid & 7) << 3;
    const int jtw   = rowp >> 4, l15w = rowp & 15, ks = cp >> 5, q0w = (cp >> 3) & 3;
    const int kWoff = (((jtw * 2 + ks) * 4 + q0w) * 16 + l15w) * 8;
    const int vWoff = lane * 72 + wv * 8;

    float4 kA0, kA1; float vA[8];
    float4 kB0, kB1; float vB[8];
    ISSUE_F(jt_lo << 6, kA0, kA1, vA);
    STAGE_F(0, kA0, kA1, vA);
    if (n > 1) ISSUE_F((jt_lo + 1) << 6, kA0, kA1, vA);
    __syncthreads();

    floatx4 acc[4] = {};
    float lsum = 0.f;
    const int iq = i0 + wv * 16 + l15;
    const int qb = i0 + wv * 16;

    for (int s = 0; s < n; s += 2) {
        const int jt = jt_lo + s;
        if (s + 2 < n) ISSUE_F((jt + 2) << 6, kB0, kB1, vB);
        if (s + 1 < n) STAGE_F(1, kA0, kA1, vA);
        compute_tile72(jt << 6, K_BUF(0), V_BUF(0), w, qb, iq, quad, l15, qf0, qf1, acc, lsum);
        barrier_nodrain();

        if (s + 1 < n) {
            if (s + 3 < n) ISSUE_F((jt + 3) << 6, kA0, kA1, vA);
            if (s + 2 < n) STAGE_F(0, kB0, kB1, vB);
            compute_tile72((jt + 1) << 6, K_BUF(1), V_BUF(1), w, qb, iq, quad, l15, qf0, qf1, acc, lsum);
            barrier_nodrain();
        }
    }

    lsum += __shfl_xor(lsum, 16, 64);
    lsum += __shfl_xor(lsum, 32, 64);
    float rinv[4];
#pragma unroll
    for (int r = 0; r < 4; ++r) {
        const float lr = __shfl(lsum, quad * 4 + r, 64);
        rinv[r] = 1.0f / lr;
    }
#pragma unroll
    for (int nt = 0; nt < 4; ++nt) {
#pragma unroll
        for (int r = 0; r < 4; ++r) {
            Ob[(size_t)(i0 + wv * 16 + quad * 4 + r) * RS + nt * 16 + l15]
                = acc[nt][r] * rinv[r];
        }
    }
}

extern "C" void kernel_launch(void* const* d_in, const int* in_sizes, int n_in,
                              void* d_out, int out_size, void* d_ws, size_t ws_size,
                              hipStream_t stream)
{
    const float* Q = (const float*)d_in[0];
    const float* K = (const float*)d_in[1];
    const float* V = (const float*)d_in[2];
    float* O = (float*)d_out;

    const size_t wsNeed = (size_t)4 * 8 * 32 * 4 * 2048 * sizeof(short);  // 16 MiB
    if (ws_size >= wsNeed) {
        short* ws = (short*)d_ws;
        hipLaunchKernelGGL(mwa_prep, dim3(1024), dim3(256), 0, stream, K, V, ws);
        hipLaunchKernelGGL(mwa_r14, dim3(1024), dim3(256), 0, stream, Q, ws, O);
    } else {
        hipLaunchKernelGGL(mwa_r11f, dim3(512), dim3(512), 0, stream, Q, K, V, O);
    }
}